// Round 12
// baseline (243.810 us; speedup 1.0000x reference)
//
#include <hip/hip_runtime.h>

#define BB 2
#define SS 2048
#define DD 1024
#define HH 16
#define HD 64
#define MM (BB*SS)   // 4096
#define KC 4                 // flash split-K chunks
#define KT_PER (SS/64/KC)    // 8 64-key groups per chunk
#define NTT 16               // 32-key tiles per chunk (512/32)
#define KSTEPS (DD/64)       // 16 K-tiles for the dWk GEMM

typedef unsigned short u16;
typedef __attribute__((ext_vector_type(8))) short bf16x8;
typedef __attribute__((ext_vector_type(4))) float f32x4;

typedef __attribute__((address_space(1))) const unsigned int* gas_t;
typedef __attribute__((address_space(3))) unsigned int* las_t;

#ifndef __has_builtin
#define __has_builtin(x) 0
#endif
#if __has_builtin(__builtin_amdgcn_exp2f)
#define EXP2F(x) __builtin_amdgcn_exp2f(x)
#else
#define EXP2F(x) __expf((x)*0.6931471805599453f)
#endif
// q pre-scale: HD^-0.5 * log2(e): scores come out of MFMA ready for exp2
#define QSCALE 0.18033688011112042f

__device__ __forceinline__ void gl_lds16(const u16* g, u16* l){
  __builtin_amdgcn_global_load_lds((gas_t)g, (las_t)l, 16, 0, 0);
}

__device__ __forceinline__ u16 f2bf(float f){
  unsigned u = __float_as_uint(f);
  u += 0x7FFF + ((u >> 16) & 1);      // RNE
  return (u16)(u >> 16);
}
__device__ __forceinline__ float bf2f(u16 h){
  return __uint_as_float(((unsigned)h) << 16);
}
__device__ __forceinline__ float dot4f(float4 a, float4 b){
  return a.x*b.x + a.y*b.y + a.z*b.z + a.w*b.w;
}

// ---- DPP wave-64 sum: row_shr 1/2/4/8 then row_bcast 15/31; total lands in
// lane 63. 6 VALU adds per value, ZERO LDS ops.
template <int CTRL>
__device__ __forceinline__ float dppadd(float x){
  int y = __builtin_amdgcn_update_dpp(0, __float_as_int(x), CTRL, 0xF, 0xF, true);
  return x + __int_as_float(y);
}
__device__ __forceinline__ float4 wsum64_f4(float4 v){
  #define DPP_ST(c) v.x=dppadd<c>(v.x); v.y=dppadd<c>(v.y); v.z=dppadd<c>(v.z); v.w=dppadd<c>(v.w);
  DPP_ST(0x111) DPP_ST(0x112) DPP_ST(0x114) DPP_ST(0x118) DPP_ST(0x142) DPP_ST(0x143)
  #undef DPP_ST
  return v;   // lane 63 holds the 4 totals
}
__device__ __forceinline__ float2 wsum64_f2(float2 v){
  #define DPP_ST(c) v.x=dppadd<c>(v.x); v.y=dppadd<c>(v.y);
  DPP_ST(0x111) DPP_ST(0x112) DPP_ST(0x114) DPP_ST(0x118) DPP_ST(0x142) DPP_ST(0x143)
  #undef DPP_ST
  return v;   // lane 63 holds the 2 totals
}

#define SB0() __builtin_amdgcn_sched_barrier(0)
#define SBAR() do { \
  __builtin_amdgcn_sched_barrier(0); \
  __builtin_amdgcn_s_barrier(); \
  __builtin_amdgcn_sched_barrier(0); \
} while (0)

// ---------------------------------------------------------------------------
// Kernel 1 (fused prologue), 1-D grid of 7172 blocks:
//  [0,2048)      convert x -> xb (bf16)
//  [2048,3072)   transpose dWk -> dWkT via LDS 64x64 tiles (coalesced stores)
//  [3072,7172)   precompute wv[i][:], cv[i]
#define NB_CONV 2048
#define NB_TRAN 1024
#define NB_PREC 4100
#define NB_PREP (NB_CONV+NB_TRAN+NB_PREC)
__global__ void prep_kernel(const float* __restrict__ x, u16* __restrict__ xb,
                            const float* __restrict__ dWk, u16* __restrict__ dWkT,
                            const float* __restrict__ Wq_, const float* __restrict__ bq_,
                            const float* __restrict__ Wk_, const float* __restrict__ bk_,
                            const float* __restrict__ Wv_, const float* __restrict__ bv_,
                            const float* __restrict__ Wo_, const float* __restrict__ bo_,
                            const float* __restrict__ dWv, const float* __restrict__ dbv,
                            float* __restrict__ wv, float* __restrict__ cv) {
  int blk = blockIdx.x, t = threadIdx.x;
  if (blk < NB_CONV) {
    size_t idx = ((size_t)blk*256 + t)*8;
    float4 a = *(const float4*)(x + idx);
    float4 b = *(const float4*)(x + idx + 4);
    union { u16 u[8]; uint4 v; } pk;
    pk.u[0]=f2bf(a.x); pk.u[1]=f2bf(a.y); pk.u[2]=f2bf(a.z); pk.u[3]=f2bf(a.w);
    pk.u[4]=f2bf(b.x); pk.u[5]=f2bf(b.y); pk.u[6]=f2bf(b.z); pk.u[7]=f2bf(b.w);
    *(uint4*)(xb + idx) = pk.v;
    return;
  }
  blk -= NB_CONV;
  if (blk < NB_TRAN) {
    // 64x64 f32 -> bf16 transpose tile: 4 i-planes x 16x16 tiles.
    int i = blk >> 8, rest = blk & 255;
    int k0 = (rest >> 4) << 6, n0 = (rest & 15) << 6;
    const float* src = dWk + (size_t)i*DD*DD;
    u16* dst = dWkT + (size_t)i*DD*DD;
    __shared__ u16 tr[64*68];            // [n][k], row stride 68 u16 (8B-aligned)
    const int krb = (t >> 4) << 2;       // 4 k-rows per thread
    const int nqb = (t & 15) << 2;       // 4 n-cols per thread
    float4 v0 = *(const float4*)(src + (size_t)(k0+krb+0)*DD + n0 + nqb);
    float4 v1 = *(const float4*)(src + (size_t)(k0+krb+1)*DD + n0 + nqb);
    float4 v2 = *(const float4*)(src + (size_t)(k0+krb+2)*DD + n0 + nqb);
    float4 v3 = *(const float4*)(src + (size_t)(k0+krb+3)*DD + n0 + nqb);
    *(uint2*)(&tr[(nqb+0)*68 + krb]) = make_uint2(
        (unsigned)f2bf(v0.x) | ((unsigned)f2bf(v1.x)<<16),
        (unsigned)f2bf(v2.x) | ((unsigned)f2bf(v3.x)<<16));
    *(uint2*)(&tr[(nqb+1)*68 + krb]) = make_uint2(
        (unsigned)f2bf(v0.y) | ((unsigned)f2bf(v1.y)<<16),
        (unsigned)f2bf(v2.y) | ((unsigned)f2bf(v3.y)<<16));
    *(uint2*)(&tr[(nqb+2)*68 + krb]) = make_uint2(
        (unsigned)f2bf(v0.z) | ((unsigned)f2bf(v1.z)<<16),
        (unsigned)f2bf(v2.z) | ((unsigned)f2bf(v3.z)<<16));
    *(uint2*)(&tr[(nqb+3)*68 + krb]) = make_uint2(
        (unsigned)f2bf(v0.w) | ((unsigned)f2bf(v1.w)<<16),
        (unsigned)f2bf(v2.w) | ((unsigned)f2bf(v3.w)<<16));
    __syncthreads();
    const int n = t >> 2, c = t & 3;
    uint2 r0 = *(uint2*)(&tr[n*68 + c*16 + 0]);
    uint2 r1 = *(uint2*)(&tr[n*68 + c*16 + 4]);
    uint2 r2 = *(uint2*)(&tr[n*68 + c*16 + 8]);
    uint2 r3 = *(uint2*)(&tr[n*68 + c*16 + 12]);
    u16* dp = dst + (size_t)(n0+n)*DD + k0 + c*16;
    *(uint4*)(dp + 0) = make_uint4(r0.x, r0.y, r1.x, r1.y);
    *(uint4*)(dp + 8) = make_uint4(r2.x, r2.y, r3.x, r3.y);
    return;
  }
  blk -= NB_TRAN;
  {
    int i = blk / 1025, row = blk % 1025;
    const float* W    = (i==0)?Wq_:(i==1)?Wk_:(i==2)?Wv_:Wo_;
    const float* bvec = (i==0)?bq_:(i==1)?bk_:(i==2)?bv_:bo_;
    const float* s = dWv + i*DD;
    __shared__ float red[256];
    float acc = 0.f;
    if (row < DD) {
      const float* r = W + (size_t)row * DD;
      for (int e = t; e < DD; e += 256) acc += r[e]*s[e];
    } else {
      for (int e = t; e < DD; e += 256) acc += bvec[e]*s[e];
    }
    red[t] = acc; __syncthreads();
    for (int off=128; off>0; off>>=1){ if(t<off) red[t]+=red[t+off]; __syncthreads(); }
    if (t==0) {
      if (row < DD) wv[i*DD + row] = red[0];
      else          cv[i] = red[0] + dbv[i];
    }
  }
}

// ---------------------------------------------------------------------------
// Kernel 2: kraw[i] = x @ dWk[i] -- 256x256 tile, 8 waves, BK=64, overlap
// schedule with 2 barriers/K-tile + counted vmcnt(6). At ~824-870 TF (run
// variance +-3%) this is at the 8-phase template's K=1024 ceiling (m248 ref:
// 848 TF) -- leave as is.
__device__ __forceinline__ void stage_half(const u16* __restrict__ g, u16* l,
                                           int k0, int half, int isA,
                                           int wid, int lane) {
  const int lr = lane>>3, lc = lane&7;
  #pragma unroll
  for (int j=0; j<2; j++) {
    const int u = wid*2 + j;
    int grow;
    if (isA) grow = ((u & 8) ? 128 + ((u & 7)<<3) : (u<<3)) + (half<<6);
    else     grow = ((u>>2)<<6) + ((u&3)<<3) + (half<<5);
    gl_lds16(g + (size_t)(grow + lr)*DD + k0 + ((lc^lr)<<3), l + grow*64);
  }
}

__device__ __forceinline__ void lda4(const u16* base, int row0, int q15, int quad,
                                     int sw, bf16x8 (&f)[4][2]) {
  #pragma unroll
  for (int mf=0; mf<4; mf++)
    #pragma unroll
    for (int kk=0; kk<2; kk++)
      f[mf][kk] = *(const bf16x8*)(base + (row0 + mf*16 + q15)*64 + (((kk*4+quad)^sw)<<3));
}
__device__ __forceinline__ void ldb2(const u16* base, int row0, int q15, int quad,
                                     int sw, bf16x8 (&f)[2][2]) {
  #pragma unroll
  for (int nf=0; nf<2; nf++)
    #pragma unroll
    for (int kk=0; kk<2; kk++)
      f[nf][kk] = *(const bf16x8*)(base + (row0 + nf*16 + q15)*64 + (((kk*4+quad)^sw)<<3));
}
// operand-swapped quadrant: acc[mf][nf] = mfma(bfrag, afrag, acc)
// -> output reg dim indexes B-rows (n), lane&15 indexes A-rows (m).
__device__ __forceinline__ void quad_mfma(const bf16x8 (&af)[4][2], const bf16x8 (&bfr)[2][2],
                                          f32x4 (&acc)[8][4], int mo, int no) {
  __builtin_amdgcn_s_setprio(1);
  #pragma unroll
  for (int kk=0; kk<2; kk++)
    #pragma unroll
    for (int mf=0; mf<4; mf++)
      #pragma unroll
      for (int nf=0; nf<2; nf++)
        acc[mo+mf][no+nf] = __builtin_amdgcn_mfma_f32_16x16x32_bf16(
            bfr[nf][kk], af[mf][kk], acc[mo+mf][no+nf], 0,0,0);
  __builtin_amdgcn_s_setprio(0);
}

__global__ __launch_bounds__(512, 2) void gemm_dwk_8ph(const u16* __restrict__ xb,
                          const u16* __restrict__ Bt, u16* __restrict__ kraw) {
  const int bid = blockIdx.x;
  const int xcd = bid & 7, rr = bid >> 3;
  const int i = xcd >> 1;
  const int mt = ((xcd & 1) << 3) | (rr & 7);
  const int ntile = rr >> 3;
  const int m0 = mt << 8, n0 = ntile << 8;
  const u16* Ab = xb + (size_t)m0*DD;
  const u16* Bb = Bt + (size_t)i*DD*DD + (size_t)n0*DD;
  u16* C = kraw + (size_t)i*MM*DD;

  const int t = threadIdx.x, wid = t>>6, lane = t&63;
  const int q15 = lane&15, quad = lane>>4, sw = q15&7;
  const int wm = wid>>2, wn = wid&3;
  const int arow = wm<<7, brow = wn<<6;   // wave's C block: 128 rows x 64 cols

  __shared__ u16 As[2][256*64];
  __shared__ u16 Bs[2][256*64];

  f32x4 acc[8][4];
  #pragma unroll
  for (int a=0;a<8;a++)
    #pragma unroll
    for (int b2=0;b2<4;b2++) acc[a][b2] = (f32x4){0.f,0.f,0.f,0.f};

  // prologue: tile0 complete + tile1's A0,B0,B1 (A1(1) staged at u=0)
  stage_half(Ab, As[0], 0,  0, 1, wid, lane);   // A0(0)
  stage_half(Bb, Bs[0], 0,  0, 0, wid, lane);   // B0(0)
  stage_half(Bb, Bs[0], 0,  1, 0, wid, lane);   // B1(0)
  stage_half(Ab, As[0], 0,  1, 1, wid, lane);   // A1(0)
  stage_half(Ab, As[1], 64, 0, 1, wid, lane);   // A0(1)
  stage_half(Bb, Bs[1], 64, 0, 0, wid, lane);   // B0(1)
  stage_half(Bb, Bs[1], 64, 1, 0, wid, lane);   // B1(1)
  SB0();
  asm volatile("s_waitcnt vmcnt(6)" ::: "memory");  // tile0's 8 loads landed
  SBAR();

  for (int u=0; u<KSTEPS; ++u) {
    const int cur = u & 1;
    const u16* Ac = As[cur]; const u16* Bc = Bs[cur];
    const int k1 = (u+1 < KSTEPS ? u+1 : KSTEPS-1) << 6;
    const int k2 = (u+2 < KSTEPS ? u+2 : KSTEPS-1) << 6;
    bf16x8 a0[4][2], a1[4][2], b0[2][2], b1[2][2];

    lda4(Ac, arow,    q15, quad, sw, a0);
    ldb2(Bc, brow,    q15, quad, sw, b0);
    ldb2(Bc, brow+32, q15, quad, sw, b1);
    stage_half(Ab, As[cur^1], k1, 1, 1, wid, lane);  // A1(u+1)
    SB0();
    quad_mfma(a0, b0, acc, 0, 0);
    quad_mfma(a0, b1, acc, 0, 2);
    SB0();
    lda4(Ac, arow+64, q15, quad, sw, a1);            // a1 reads overlap barrier
    SB0();
    __builtin_amdgcn_s_barrier();                    // mid: a0,b0,b1 consumed
    SB0();
    stage_half(Ab, As[cur], k2, 0, 1, wid, lane);    // A0(u+2)
    stage_half(Bb, Bs[cur], k2, 0, 0, wid, lane);    // B0(u+2)
    stage_half(Bb, Bs[cur], k2, 1, 0, wid, lane);    // B1(u+2)
    SB0();
    quad_mfma(a1, b1, acc, 4, 2);
    quad_mfma(a1, b0, acc, 4, 0);
    SB0();
    asm volatile("s_waitcnt vmcnt(6)" ::: "memory"); // tile u+1 fully landed
    __builtin_amdgcn_s_barrier();
    SB0();
  }

  // epilogue: reg dim = n (operand swap) -> pack 4 consecutive n per lane
  #pragma unroll
  for (int mf=0; mf<8; mf++) {
    const int m = m0 + arow + mf*16 + q15;
    u16* Crow = C + (size_t)m*DD + n0 + brow;
    #pragma unroll
    for (int nf=0; nf<4; nf++) {
      unsigned u0 = (unsigned)f2bf(acc[mf][nf][0]) | ((unsigned)f2bf(acc[mf][nf][1]) << 16);
      unsigned u1 = (unsigned)f2bf(acc[mf][nf][2]) | ((unsigned)f2bf(acc[mf][nf][3]) << 16);
      *(uint2*)(Crow + nf*16 + quad*4) = make_uint2(u0, u1);
    }
  }
}

// ---------------------------------------------------------------------------
// Kernel 3: delta i=0..2 -> q' (pre-scaled) + k planes bf16, Vw[b][h][s].
__global__ void delta_qkv_kernel(const float* __restrict__ x, const u16* __restrict__ kraw,
                                 const float* __restrict__ dbw, const float* __restrict__ dbb,
                                 const float* __restrict__ wv, const float* __restrict__ cv,
                                 u16* __restrict__ qk, float* __restrict__ Vw) {
  int m = blockIdx.x, t = threadIdx.x, w = t>>6, lane = t&63;
  const float* xr = x + (size_t)m*DD;
  float4 xv = *(const float4*)(xr + t*4);
  __shared__ float4 part[3][4];
  float4 kvs[3];
  #pragma unroll
  for (int i=0;i<3;i++) {
    ushort4 ku = *(const ushort4*)(kraw + (size_t)i*MM*DD + (size_t)m*DD + t*4);
    float4 kv = make_float4(bf2f(ku.x), bf2f(ku.y), bf2f(ku.z), bf2f(ku.w));
    kvs[i] = kv;
    float4 bwv = *(const float4*)(dbw + i*DD + t*4);
    float4 wvv = *(const float4*)(wv  + i*DD + t*4);
    float4 red = make_float4(dot4f(kv,kv), dot4f(kv,xv), dot4f(xv,bwv), dot4f(xv,wvv));
    red = wsum64_f4(red);
    if (lane==63) part[i][w] = red;
  }
  __syncthreads();
  float cc[3];
  #pragma unroll
  for (int i=0;i<3;i++) {
    float4 r0=part[i][0], r1=part[i][1], r2=part[i][2], r3=part[i][3];
    float s0=r0.x+r1.x+r2.x+r3.x, s1=r0.y+r1.y+r2.y+r3.y;
    float s2=r0.z+r1.z+r2.z+r3.z, s3=r0.w+r1.w+r2.w+r3.w;
    float nrmE = sqrtf(s0) + 1e-8f;
    float kdh  = s1 / nrmE;
    float beta = 2.f / (1.f + __expf(-(s2 + dbb[i])));
    float vs   = s3 + cv[i];
    cc[i] = beta * (vs - kdh) / nrmE;
  }
  {
    float c = cc[0]; float4 kv = kvs[0];
    ushort4 ou;
    ou.x = f2bf((xv.x + c*kv.x)*QSCALE); ou.y = f2bf((xv.y + c*kv.y)*QSCALE);
    ou.z = f2bf((xv.z + c*kv.z)*QSCALE); ou.w = f2bf((xv.w + c*kv.w)*QSCALE);
    *(ushort4*)(qk + (size_t)m*DD + t*4) = ou;
  }
  {
    float c = cc[1]; float4 kv = kvs[1];
    ushort4 ou;
    ou.x = f2bf(xv.x + c*kv.x); ou.y = f2bf(xv.y + c*kv.y);
    ou.z = f2bf(xv.z + c*kv.z); ou.w = f2bf(xv.w + c*kv.w);
    *(ushort4*)(qk + (size_t)MM*DD + (size_t)m*DD + t*4) = ou;
  }
  {
    float c = cc[2]; float4 kv = kvs[2];
    float4 vv = make_float4(xv.x + c*kv.x, xv.y + c*kv.y, xv.z + c*kv.z, xv.w + c*kv.w);
    float4 w3 = *(const float4*)(wv + 3*DD + t*4);
    float s = dot4f(vv, w3);
    #pragma unroll
    for (int off=1; off<16; off<<=1) s += __shfl_xor(s, off);
    if ((lane & 15) == 0) {
      int head = t >> 4;
      int b = m >> 11, srow = m & (SS-1);
      Vw[((size_t)(b*HH + head))*SS + srow] = s;
    }
  }
}

// ---------------------------------------------------------------------------
// Kernel 4: split-K QK^T flash. grid (32, 16, BB*KC), block 256.
// v8: BARRIER-FREE streaming. Five LDS-staged variants all hit 40-50us with
// occupancy/LDS-reads/traffic individually refuted as the cause -- the shared
// machinery was the per-tile barrier lock-step. This version has ZERO in-loop
// barriers and ZERO K LDS: wave w owns kt=4j+w, K fragments read straight
// from global (L2-resident k-plane) into registers with a depth-1 software
// pipeline; all 64 q-fragments in regs (R8/R11-proven, FETCH stays ~38MB).
// Addresses = the old post-swizzle layout: kbase+(kt*32+q15)*DD+kk*32+quad*8.
// One __syncthreads before the 2KB cross-wave l/pv reduce (R8 epilogue).
// launch_bounds(256,2): 128-VGPR cap, est ~108.
__global__ __launch_bounds__(256, 2) void flash_mfma(const u16* __restrict__ qb,
     const u16* __restrict__ kb, const float* __restrict__ Vw,
     float* __restrict__ l_arr, float* __restrict__ pv_arr) {
  const int qt = blockIdx.x, h = blockIdx.y;
  const int b = blockIdx.z >> 2, kc = blockIdx.z & 3;
  const int t = threadIdx.x, w = t>>6, lane = t&63, q15 = lane&15, quad = lane>>4;
  __shared__ float2 red2[4*64];         // 2 KB cross-wave l/pv partials
  const size_t hb = (size_t)h*HD;
  const u16* kbase = kb + (size_t)(b*SS + kc*KT_PER*64)*DD + hb;
  const float* vwb = Vw + (size_t)(b*HH + h)*SS + kc*KT_PER*64;

  // ALL 64 q-rows in regs (8x 16B loads/lane, qk slab L2/L3-resident)
  bf16x8 qf[4][2];
  #pragma unroll
  for (int qt2=0; qt2<4; qt2++) {
    const u16* qrow = qb + (size_t)(b*SS + qt*64 + qt2*16 + q15)*DD + hb;
    qf[qt2][0] = *(const bf16x8*)(qrow + quad*8);
    qf[qt2][1] = *(const bf16x8*)(qrow + 32 + quad*8);
  }
  float l_acc[4] = {0.f,0.f,0.f,0.f}, pv_acc[4] = {0.f,0.f,0.f,0.f};

  // wave w owns kt = 4j+w. Depth-1 software pipeline, direct-global K reads.
  bf16x8 c00, c01, c10, c11; float4 cva0, cva1;
  {
    const u16* kr = kbase + (size_t)(w*32 + q15)*DD + quad*8;
    c00 = *(const bf16x8*)(kr);
    c01 = *(const bf16x8*)(kr + 32);
    c10 = *(const bf16x8*)(kr + 16*DD);
    c11 = *(const bf16x8*)(kr + 16*DD + 32);
    cva0 = *(const float4*)(vwb + w*32 + quad*4);
    cva1 = *(const float4*)(vwb + w*32 + 16 + quad*4);
  }
  #pragma unroll
  for (int j=0; j<4; ++j) {
    bf16x8 n00, n01, n10, n11; float4 nva0, nva1;
    if (j < 3) {
      const int ktn = (j+1)*4 + w;
      const u16* kr = kbase + (size_t)(ktn*32 + q15)*DD + quad*8;
      n00 = *(const bf16x8*)(kr);
      n01 = *(const bf16x8*)(kr + 32);
      n10 = *(const bf16x8*)(kr + 16*DD);
      n11 = *(const bf16x8*)(kr + 16*DD + 32);
      nva0 = *(const float4*)(vwb + ktn*32 + quad*4);
      nva1 = *(const float4*)(vwb + ktn*32 + 16 + quad*4);
    }
    // compute tile j (keys kt*32 + {0,16} + quad*4+r vs all 64 q)
    #pragma unroll
    for (int qt2=0; qt2<4; qt2++) {
      f32x4 S0 = (f32x4){0.f,0.f,0.f,0.f}, S1 = (f32x4){0.f,0.f,0.f,0.f};
      S0 = __builtin_amdgcn_mfma_f32_16x16x32_bf16(c00, qf[qt2][0], S0, 0,0,0);
      S0 = __builtin_amdgcn_mfma_f32_16x16x32_bf16(c01, qf[qt2][1], S0, 0,0,0);
      S1 = __builtin_amdgcn_mfma_f32_16x16x32_bf16(c10, qf[qt2][0], S1, 0,0,0);
      S1 = __builtin_amdgcn_mfma_f32_16x16x32_bf16(c11, qf[qt2][1], S1, 0,0,0);
      {
        float p0 = EXP2F(fminf(S0[0], 30.f));
        float p1 = EXP2F(fminf(S0[1], 30.f));
        float p2 = EXP2F(fminf(S0[2], 30.f));
        float p3 = EXP2F(fminf(S0[3], 30.f));
        l_acc[qt2]  += (p0 + p1) + (p2 + p3);
        pv_acc[qt2] += p0*cva0.x + p1*cva0.y + p2*cva0.z + p3*cva0.w;
      }
      {
        float p0 = EXP2F(fminf(S1[0], 30.f));
        float p1 = EXP2F(fminf(S1[1], 30.f));
        float p2 = EXP2F(fminf(S1[2], 30.f));
        float p3 = EXP2F(fminf(S1[3], 30.f));
        l_acc[qt2]  += (p0 + p1) + (p2 + p3);
        pv_acc[qt2] += p0*cva1.x + p1*cva1.y + p2*cva1.z + p3*cva1.w;
      }
    }
    if (j < 3) { c00=n00; c01=n01; c10=n10; c11=n11; cva0=nva0; cva1=nva1; }
  }
  // quad-reduce (lanes sharing q column q15) -> wave partials
  #pragma unroll
  for (int qt2=0; qt2<4; qt2++) {
    l_acc[qt2]  += __shfl_xor(l_acc[qt2], 16);  l_acc[qt2]  += __shfl_xor(l_acc[qt2], 32);
    pv_acc[qt2] += __shfl_xor(pv_acc[qt2], 16); pv_acc[qt2] += __shfl_xor(pv_acc[qt2], 32);
  }
  if (lane < 16) {
    #pragma unroll
    for (int qt2=0; qt2<4; qt2++)
      red2[w*64 + qt2*16 + lane] = make_float2(l_acc[qt2], pv_acc[qt2]);
  }
  __syncthreads();
  if (t < 64) {
    float2 p0 = red2[t], p1 = red2[64+t], p2 = red2[128+t], p3 = red2[192+t];
    float ls = (p0.x+p1.x) + (p2.x+p3.x);
    float ps = (p0.y+p1.y) + (p2.y+p3.y);
    int tok = b*SS + qt*64 + t;
    size_t idx = ((size_t)kc*MM + tok)*HH + h;
    l_arr[idx]  = ls;
    pv_arr[idx] = ps;
  }
}

// ---------------------------------------------------------------------------
// Kernel 5: v3 = sum_h (sum_kc pv)/(sum_kc l), delta #3 + LayerNorm. grid MM.
__global__ void final_kernel(const float* __restrict__ x, const u16* __restrict__ kraw3,
                             const float* __restrict__ l_arr, const float* __restrict__ pv_arr,
                             const float* __restrict__ dbw, const float* __restrict__ dbb,
                             const float* __restrict__ cv,
                             const float* __restrict__ ln_g, const float* __restrict__ ln_b,
                             float* __restrict__ out) {
  int m = blockIdx.x, t = threadIdx.x, w = t>>6, lane = t&63;
  const float* xr = x     + (size_t)m*DD;
  const u16*   kr = kraw3 + (size_t)m*DD;
  float4 xv  = *(const float4*)(xr + t*4);
  ushort4 ku = *(const ushort4*)(kr + t*4);
  float4 kv  = make_float4(bf2f(ku.x), bf2f(ku.y), bf2f(ku.z), bf2f(ku.w));
  float4 bwv = *(const float4*)(dbw + 3*DD + t*4);
  __shared__ float4 part[4];
  __shared__ float2 part2[4];
  __shared__ float v3s;
  if (t < 16) {
    float lsum = 0.f, psum = 0.f;
    #pragma unroll
    for (int kc=0; kc<KC; kc++) {
      size_t idx = ((size_t)kc*MM + m)*HH + t;
      lsum += l_arr[idx];
      psum += pv_arr[idx];
    }
    float val = psum / lsum;
    #pragma unroll
    for (int off=1; off<16; off<<=1) val += __shfl_xor(val, off);
    if (t==0) v3s = val;
  }
  float4 red = make_float4(dot4f(kv,kv), dot4f(kv,xv), dot4f(xv,bwv), 0.f);
  red = wsum64_f4(red);
  if (lane==63) part[w] = red;
  __syncthreads();
  float4 r0=part[0], r1=part[1], r2=part[2], r3=part[3];
  float s0=r0.x+r1.x+r2.x+r3.x, s1=r0.y+r1.y+r2.y+r3.y, s2=r0.z+r1.z+r2.z+r3.z;
  float nrmE = sqrtf(s0) + 1e-8f;
  float kdh  = s1 / nrmE;
  float beta = 2.f / (1.f + __expf(-(s2 + dbb[3])));
  float v3   = v3s + cv[3];
  float c = beta * (v3 - kdh) / nrmE;
  float y0 = xv.x + c*kv.x, y1 = xv.y + c*kv.y, y2 = xv.z + c*kv.z, y3 = xv.w + c*kv.w;
  float2 rr = make_float2(y0+y1+y2+y3, y0*y0+y1*y1+y2*y2+y3*y3);
  rr = wsum64_f2(rr);
  if (lane==63) part2[w] = rr;
  __syncthreads();
  float ssum = part2[0].x+part2[1].x+part2[2].x+part2[3].x;
  float ssq  = part2[0].y+part2[1].y+part2[2].y+part2[3].y;
  float mu   = ssum * (1.f/DD);
  float var  = ssq * (1.f/DD) - mu*mu;
  float rstd = rsqrtf(var + 1e-5f);
  float4 g  = *(const float4*)(ln_g + t*4);
  float4 bb = *(const float4*)(ln_b + t*4);
  float4 ov;
  ov.x = (y0-mu)*rstd*g.x + bb.x;
  ov.y = (y1-mu)*rstd*g.y + bb.y;
  ov.z = (y2-mu)*rstd*g.z + bb.z;
  ov.w = (y3-mu)*rstd*g.w + bb.w;
  *(float4*)(out + (size_t)m*DD + t*4) = ov;
}

// ---------------------------------------------------------------------------
extern "C" void kernel_launch(void* const* d_in, const int* in_sizes, int n_in,
                              void* d_out, int out_size, void* d_ws, size_t ws_size,
                              hipStream_t stream) {
  const float* x    = (const float*)d_in[0];
  const float* Wq_  = (const float*)d_in[1];
  const float* bq_  = (const float*)d_in[2];
  const float* Wk_  = (const float*)d_in[3];
  const float* bk_  = (const float*)d_in[4];
  const float* Wv_  = (const float*)d_in[5];
  const float* bv_  = (const float*)d_in[6];
  const float* Wo_  = (const float*)d_in[7];
  const float* bo_  = (const float*)d_in[8];
  const float* dWk  = (const float*)d_in[9];
  const float* dbw  = (const float*)d_in[10];
  const float* dbb  = (const float*)d_in[11];
  const float* dWv  = (const float*)d_in[12];
  const float* dbv  = (const float*)d_in[13];
  const float* ln_g = (const float*)d_in[14];
  const float* ln_b = (const float*)d_in[15];
  float* out = (float*)d_out;
  char* WS = (char*)d_ws;

  // workspace layout (bytes):
  float* wv     = (float*)WS;                                 // 16 KB
  float* cv     = (float*)(WS + 16384);                       // 256 B
  u16*   kraw   = (u16*)  (WS + 16640);                       // 4*MM*DD bf16 = 33.5 MB
  u16*   qk     = (u16*)  (WS + 16640 + (size_t)4*MM*DD*2);   // 2*MM*DD bf16 = 16.8 MB
  u16*   dWkT   = (u16*)  (WS + 16640 + (size_t)6*MM*DD*2);   // 8.4 MB
  u16*   xb     = (u16*)  (WS + 16640 + (size_t)6*MM*DD*2 + (size_t)4*DD*DD*2); // 8.4 MB
  char*  tail   = WS + 16640 + (size_t)6*MM*DD*2 + (size_t)8*DD*DD*2;
  float* Vw     = (float*)tail;                               // BB*HH*SS f32 = 256 KB
  float* l_arr  = (float*)(tail + (size_t)BB*HH*SS*4);        // KC*MM*HH f32 = 1 MB
  float* pv_arr = (float*)(tail + (size_t)BB*HH*SS*4 + (size_t)KC*MM*HH*4); // 1 MB

  prep_kernel<<<NB_PREP, 256, 0, stream>>>(
      x, xb, dWk, dWkT, Wq_,bq_,Wk_,bk_,Wv_,bv_,Wo_,bo_, dWv, dbv, wv, cv);
  gemm_dwk_8ph<<<256, 512, 0, stream>>>(xb, dWkT, kraw);
  delta_qkv_kernel<<<MM, 256, 0, stream>>>(x, kraw, dbw, dbb, wv, cv, qk, Vw);
  flash_mfma<<<dim3(SS/64, HH, BB*KC), 256, 0, stream>>>(
      qk, qk + (size_t)MM*DD, Vw, l_arr, pv_arr);
  final_kernel<<<MM, 256, 0, stream>>>(x, kraw + 3*(size_t)MM*DD, l_arr, pv_arr,
                                       dbw, dbb, cv, ln_g, ln_b, out);
}

// Round 13
// 215.126 us; speedup vs baseline: 1.1333x; 1.1333x over previous
//
#include <hip/hip_runtime.h>

#define BB 2
#define SS 2048
#define DD 1024
#define HH 16
#define HD 64
#define MM (BB*SS)   // 4096
#define KC 4                 // flash split-K chunks
#define KT_PER (SS/64/KC)    // 8 64-key tiles per chunk
#define QB 128               // q-rows per flash block
#define KSTEPS (DD/64)       // 16 K-tiles for the dWk GEMM

typedef unsigned short u16;
typedef __attribute__((ext_vector_type(8))) short bf16x8;
typedef __attribute__((ext_vector_type(4))) float f32x4;

typedef __attribute__((address_space(1))) const unsigned int* gas_t;
typedef __attribute__((address_space(3))) unsigned int* las_t;

#ifndef __has_builtin
#define __has_builtin(x) 0
#endif
#if __has_builtin(__builtin_amdgcn_exp2f)
#define EXP2F(x) __builtin_amdgcn_exp2f(x)
#else
#define EXP2F(x) __expf((x)*0.6931471805599453f)
#endif
// q pre-scale: HD^-0.5 * log2(e): scores come out of MFMA ready for exp2
#define QSCALE 0.18033688011112042f

__device__ __forceinline__ void gl_lds16(const u16* g, u16* l){
  __builtin_amdgcn_global_load_lds((gas_t)g, (las_t)l, 16, 0, 0);
}

__device__ __forceinline__ u16 f2bf(float f){
  unsigned u = __float_as_uint(f);
  u += 0x7FFF + ((u >> 16) & 1);      // RNE
  return (u16)(u >> 16);
}
__device__ __forceinline__ float bf2f(u16 h){
  return __uint_as_float(((unsigned)h) << 16);
}
__device__ __forceinline__ float dot4f(float4 a, float4 b){
  return a.x*b.x + a.y*b.y + a.z*b.z + a.w*b.w;
}

// ---- DPP wave-64 sum: row_shr 1/2/4/8 then row_bcast 15/31; total lands in
// lane 63. 6 VALU adds per value, ZERO LDS ops.
template <int CTRL>
__device__ __forceinline__ float dppadd(float x){
  int y = __builtin_amdgcn_update_dpp(0, __float_as_int(x), CTRL, 0xF, 0xF, true);
  return x + __int_as_float(y);
}
__device__ __forceinline__ float4 wsum64_f4(float4 v){
  #define DPP_ST(c) v.x=dppadd<c>(v.x); v.y=dppadd<c>(v.y); v.z=dppadd<c>(v.z); v.w=dppadd<c>(v.w);
  DPP_ST(0x111) DPP_ST(0x112) DPP_ST(0x114) DPP_ST(0x118) DPP_ST(0x142) DPP_ST(0x143)
  #undef DPP_ST
  return v;   // lane 63 holds the 4 totals
}
__device__ __forceinline__ float2 wsum64_f2(float2 v){
  #define DPP_ST(c) v.x=dppadd<c>(v.x); v.y=dppadd<c>(v.y);
  DPP_ST(0x111) DPP_ST(0x112) DPP_ST(0x114) DPP_ST(0x118) DPP_ST(0x142) DPP_ST(0x143)
  #undef DPP_ST
  return v;   // lane 63 holds the 2 totals
}

#define SB0() __builtin_amdgcn_sched_barrier(0)
#define SBAR() do { \
  __builtin_amdgcn_sched_barrier(0); \
  __builtin_amdgcn_s_barrier(); \
  __builtin_amdgcn_sched_barrier(0); \
} while (0)

// ---------------------------------------------------------------------------
// Kernel 1 (fused prologue), 1-D grid of 7172 blocks:
//  [0,2048)      convert x -> xb (bf16)
//  [2048,3072)   transpose dWk -> dWkT via LDS 64x64 tiles (coalesced stores)
//  [3072,7172)   precompute wv[i][:], cv[i]
#define NB_CONV 2048
#define NB_TRAN 1024
#define NB_PREC 4100
#define NB_PREP (NB_CONV+NB_TRAN+NB_PREC)
__global__ void prep_kernel(const float* __restrict__ x, u16* __restrict__ xb,
                            const float* __restrict__ dWk, u16* __restrict__ dWkT,
                            const float* __restrict__ Wq_, const float* __restrict__ bq_,
                            const float* __restrict__ Wk_, const float* __restrict__ bk_,
                            const float* __restrict__ Wv_, const float* __restrict__ bv_,
                            const float* __restrict__ Wo_, const float* __restrict__ bo_,
                            const float* __restrict__ dWv, const float* __restrict__ dbv,
                            float* __restrict__ wv, float* __restrict__ cv) {
  int blk = blockIdx.x, t = threadIdx.x;
  if (blk < NB_CONV) {
    size_t idx = ((size_t)blk*256 + t)*8;
    float4 a = *(const float4*)(x + idx);
    float4 b = *(const float4*)(x + idx + 4);
    union { u16 u[8]; uint4 v; } pk;
    pk.u[0]=f2bf(a.x); pk.u[1]=f2bf(a.y); pk.u[2]=f2bf(a.z); pk.u[3]=f2bf(a.w);
    pk.u[4]=f2bf(b.x); pk.u[5]=f2bf(b.y); pk.u[6]=f2bf(b.z); pk.u[7]=f2bf(b.w);
    *(uint4*)(xb + idx) = pk.v;
    return;
  }
  blk -= NB_CONV;
  if (blk < NB_TRAN) {
    // 64x64 f32 -> bf16 transpose tile: 4 i-planes x 16x16 tiles.
    int i = blk >> 8, rest = blk & 255;
    int k0 = (rest >> 4) << 6, n0 = (rest & 15) << 6;
    const float* src = dWk + (size_t)i*DD*DD;
    u16* dst = dWkT + (size_t)i*DD*DD;
    __shared__ u16 tr[64*68];            // [n][k], row stride 68 u16 (8B-aligned)
    const int krb = (t >> 4) << 2;       // 4 k-rows per thread
    const int nqb = (t & 15) << 2;       // 4 n-cols per thread
    float4 v0 = *(const float4*)(src + (size_t)(k0+krb+0)*DD + n0 + nqb);
    float4 v1 = *(const float4*)(src + (size_t)(k0+krb+1)*DD + n0 + nqb);
    float4 v2 = *(const float4*)(src + (size_t)(k0+krb+2)*DD + n0 + nqb);
    float4 v3 = *(const float4*)(src + (size_t)(k0+krb+3)*DD + n0 + nqb);
    *(uint2*)(&tr[(nqb+0)*68 + krb]) = make_uint2(
        (unsigned)f2bf(v0.x) | ((unsigned)f2bf(v1.x)<<16),
        (unsigned)f2bf(v2.x) | ((unsigned)f2bf(v3.x)<<16));
    *(uint2*)(&tr[(nqb+1)*68 + krb]) = make_uint2(
        (unsigned)f2bf(v0.y) | ((unsigned)f2bf(v1.y)<<16),
        (unsigned)f2bf(v2.y) | ((unsigned)f2bf(v3.y)<<16));
    *(uint2*)(&tr[(nqb+2)*68 + krb]) = make_uint2(
        (unsigned)f2bf(v0.z) | ((unsigned)f2bf(v1.z)<<16),
        (unsigned)f2bf(v2.z) | ((unsigned)f2bf(v3.z)<<16));
    *(uint2*)(&tr[(nqb+3)*68 + krb]) = make_uint2(
        (unsigned)f2bf(v0.w) | ((unsigned)f2bf(v1.w)<<16),
        (unsigned)f2bf(v2.w) | ((unsigned)f2bf(v3.w)<<16));
    __syncthreads();
    const int n = t >> 2, c = t & 3;
    uint2 r0 = *(uint2*)(&tr[n*68 + c*16 + 0]);
    uint2 r1 = *(uint2*)(&tr[n*68 + c*16 + 4]);
    uint2 r2 = *(uint2*)(&tr[n*68 + c*16 + 8]);
    uint2 r3 = *(uint2*)(&tr[n*68 + c*16 + 12]);
    u16* dp = dst + (size_t)(n0+n)*DD + k0 + c*16;
    *(uint4*)(dp + 0) = make_uint4(r0.x, r0.y, r1.x, r1.y);
    *(uint4*)(dp + 8) = make_uint4(r2.x, r2.y, r3.x, r3.y);
    return;
  }
  blk -= NB_TRAN;
  {
    int i = blk / 1025, row = blk % 1025;
    const float* W    = (i==0)?Wq_:(i==1)?Wk_:(i==2)?Wv_:Wo_;
    const float* bvec = (i==0)?bq_:(i==1)?bk_:(i==2)?bv_:bo_;
    const float* s = dWv + i*DD;
    __shared__ float red[256];
    float acc = 0.f;
    if (row < DD) {
      const float* r = W + (size_t)row * DD;
      for (int e = t; e < DD; e += 256) acc += r[e]*s[e];
    } else {
      for (int e = t; e < DD; e += 256) acc += bvec[e]*s[e];
    }
    red[t] = acc; __syncthreads();
    for (int off=128; off>0; off>>=1){ if(t<off) red[t]+=red[t+off]; __syncthreads(); }
    if (t==0) {
      if (row < DD) wv[i*DD + row] = red[0];
      else          cv[i] = red[0] + dbv[i];
    }
  }
}

// ---------------------------------------------------------------------------
// Kernel 2: kraw[i] = x @ dWk[i] -- 256x256 tile, 8 waves, BK=64, overlap
// schedule with 2 barriers/K-tile + counted vmcnt(6). At ~824-870 TF this is
// at the 8-phase template's K=1024 ceiling (m248 ref: 848 TF) -- leave as is.
__device__ __forceinline__ void stage_half(const u16* __restrict__ g, u16* l,
                                           int k0, int half, int isA,
                                           int wid, int lane) {
  const int lr = lane>>3, lc = lane&7;
  #pragma unroll
  for (int j=0; j<2; j++) {
    const int u = wid*2 + j;
    int grow;
    if (isA) grow = ((u & 8) ? 128 + ((u & 7)<<3) : (u<<3)) + (half<<6);
    else     grow = ((u>>2)<<6) + ((u&3)<<3) + (half<<5);
    gl_lds16(g + (size_t)(grow + lr)*DD + k0 + ((lc^lr)<<3), l + grow*64);
  }
}

__device__ __forceinline__ void lda4(const u16* base, int row0, int q15, int quad,
                                     int sw, bf16x8 (&f)[4][2]) {
  #pragma unroll
  for (int mf=0; mf<4; mf++)
    #pragma unroll
    for (int kk=0; kk<2; kk++)
      f[mf][kk] = *(const bf16x8*)(base + (row0 + mf*16 + q15)*64 + (((kk*4+quad)^sw)<<3));
}
__device__ __forceinline__ void ldb2(const u16* base, int row0, int q15, int quad,
                                     int sw, bf16x8 (&f)[2][2]) {
  #pragma unroll
  for (int nf=0; nf<2; nf++)
    #pragma unroll
    for (int kk=0; kk<2; kk++)
      f[nf][kk] = *(const bf16x8*)(base + (row0 + nf*16 + q15)*64 + (((kk*4+quad)^sw)<<3));
}
// operand-swapped quadrant: acc[mf][nf] = mfma(bfrag, afrag, acc)
// -> output reg dim indexes B-rows (n), lane&15 indexes A-rows (m).
__device__ __forceinline__ void quad_mfma(const bf16x8 (&af)[4][2], const bf16x8 (&bfr)[2][2],
                                          f32x4 (&acc)[8][4], int mo, int no) {
  __builtin_amdgcn_s_setprio(1);
  #pragma unroll
  for (int kk=0; kk<2; kk++)
    #pragma unroll
    for (int mf=0; mf<4; mf++)
      #pragma unroll
      for (int nf=0; nf<2; nf++)
        acc[mo+mf][no+nf] = __builtin_amdgcn_mfma_f32_16x16x32_bf16(
            bfr[nf][kk], af[mf][kk], acc[mo+mf][no+nf], 0,0,0);
  __builtin_amdgcn_s_setprio(0);
}

__global__ __launch_bounds__(512, 2) void gemm_dwk_8ph(const u16* __restrict__ xb,
                          const u16* __restrict__ Bt, u16* __restrict__ kraw) {
  const int bid = blockIdx.x;
  const int xcd = bid & 7, rr = bid >> 3;
  const int i = xcd >> 1;
  const int mt = ((xcd & 1) << 3) | (rr & 7);
  const int ntile = rr >> 3;
  const int m0 = mt << 8, n0 = ntile << 8;
  const u16* Ab = xb + (size_t)m0*DD;
  const u16* Bb = Bt + (size_t)i*DD*DD + (size_t)n0*DD;
  u16* C = kraw + (size_t)i*MM*DD;

  const int t = threadIdx.x, wid = t>>6, lane = t&63;
  const int q15 = lane&15, quad = lane>>4, sw = q15&7;
  const int wm = wid>>2, wn = wid&3;
  const int arow = wm<<7, brow = wn<<6;   // wave's C block: 128 rows x 64 cols

  __shared__ u16 As[2][256*64];
  __shared__ u16 Bs[2][256*64];

  f32x4 acc[8][4];
  #pragma unroll
  for (int a=0;a<8;a++)
    #pragma unroll
    for (int b2=0;b2<4;b2++) acc[a][b2] = (f32x4){0.f,0.f,0.f,0.f};

  // prologue: tile0 complete + tile1's A0,B0,B1 (A1(1) staged at u=0)
  stage_half(Ab, As[0], 0,  0, 1, wid, lane);   // A0(0)
  stage_half(Bb, Bs[0], 0,  0, 0, wid, lane);   // B0(0)
  stage_half(Bb, Bs[0], 0,  1, 0, wid, lane);   // B1(0)
  stage_half(Ab, As[0], 0,  1, 1, wid, lane);   // A1(0)
  stage_half(Ab, As[1], 64, 0, 1, wid, lane);   // A0(1)
  stage_half(Bb, Bs[1], 64, 0, 0, wid, lane);   // B0(1)
  stage_half(Bb, Bs[1], 64, 1, 0, wid, lane);   // B1(1)
  SB0();
  asm volatile("s_waitcnt vmcnt(6)" ::: "memory");  // tile0's 8 loads landed
  SBAR();

  for (int u=0; u<KSTEPS; ++u) {
    const int cur = u & 1;
    const u16* Ac = As[cur]; const u16* Bc = Bs[cur];
    const int k1 = (u+1 < KSTEPS ? u+1 : KSTEPS-1) << 6;
    const int k2 = (u+2 < KSTEPS ? u+2 : KSTEPS-1) << 6;
    bf16x8 a0[4][2], a1[4][2], b0[2][2], b1[2][2];

    lda4(Ac, arow,    q15, quad, sw, a0);
    ldb2(Bc, brow,    q15, quad, sw, b0);
    ldb2(Bc, brow+32, q15, quad, sw, b1);
    stage_half(Ab, As[cur^1], k1, 1, 1, wid, lane);  // A1(u+1)
    SB0();
    quad_mfma(a0, b0, acc, 0, 0);
    quad_mfma(a0, b1, acc, 0, 2);
    SB0();
    lda4(Ac, arow+64, q15, quad, sw, a1);            // a1 reads overlap barrier
    SB0();
    __builtin_amdgcn_s_barrier();                    // mid: a0,b0,b1 consumed
    SB0();
    stage_half(Ab, As[cur], k2, 0, 1, wid, lane);    // A0(u+2)
    stage_half(Bb, Bs[cur], k2, 0, 0, wid, lane);    // B0(u+2)
    stage_half(Bb, Bs[cur], k2, 1, 0, wid, lane);    // B1(u+2)
    SB0();
    quad_mfma(a1, b1, acc, 4, 2);
    quad_mfma(a1, b0, acc, 4, 0);
    SB0();
    asm volatile("s_waitcnt vmcnt(6)" ::: "memory"); // tile u+1 fully landed
    __builtin_amdgcn_s_barrier();
    SB0();
  }

  // epilogue: reg dim = n (operand swap) -> pack 4 consecutive n per lane
  #pragma unroll
  for (int mf=0; mf<8; mf++) {
    const int m = m0 + arow + mf*16 + q15;
    u16* Crow = C + (size_t)m*DD + n0 + brow;
    #pragma unroll
    for (int nf=0; nf<4; nf++) {
      unsigned u0 = (unsigned)f2bf(acc[mf][nf][0]) | ((unsigned)f2bf(acc[mf][nf][1]) << 16);
      unsigned u1 = (unsigned)f2bf(acc[mf][nf][2]) | ((unsigned)f2bf(acc[mf][nf][3]) << 16);
      *(uint2*)(Crow + nf*16 + quad*4) = make_uint2(u0, u1);
    }
  }
}

// ---------------------------------------------------------------------------
// Kernel 3: delta i=0..2 -> q' (pre-scaled) + k planes bf16, Vw[b][h][s].
__global__ void delta_qkv_kernel(const float* __restrict__ x, const u16* __restrict__ kraw,
                                 const float* __restrict__ dbw, const float* __restrict__ dbb,
                                 const float* __restrict__ wv, const float* __restrict__ cv,
                                 u16* __restrict__ qk, float* __restrict__ Vw) {
  int m = blockIdx.x, t = threadIdx.x, w = t>>6, lane = t&63;
  const float* xr = x + (size_t)m*DD;
  float4 xv = *(const float4*)(xr + t*4);
  __shared__ float4 part[3][4];
  float4 kvs[3];
  #pragma unroll
  for (int i=0;i<3;i++) {
    ushort4 ku = *(const ushort4*)(kraw + (size_t)i*MM*DD + (size_t)m*DD + t*4);
    float4 kv = make_float4(bf2f(ku.x), bf2f(ku.y), bf2f(ku.z), bf2f(ku.w));
    kvs[i] = kv;
    float4 bwv = *(const float4*)(dbw + i*DD + t*4);
    float4 wvv = *(const float4*)(wv  + i*DD + t*4);
    float4 red = make_float4(dot4f(kv,kv), dot4f(kv,xv), dot4f(xv,bwv), dot4f(xv,wvv));
    red = wsum64_f4(red);
    if (lane==63) part[i][w] = red;
  }
  __syncthreads();
  float cc[3];
  #pragma unroll
  for (int i=0;i<3;i++) {
    float4 r0=part[i][0], r1=part[i][1], r2=part[i][2], r3=part[i][3];
    float s0=r0.x+r1.x+r2.x+r3.x, s1=r0.y+r1.y+r2.y+r3.y;
    float s2=r0.z+r1.z+r2.z+r3.z, s3=r0.w+r1.w+r2.w+r3.w;
    float nrmE = sqrtf(s0) + 1e-8f;
    float kdh  = s1 / nrmE;
    float beta = 2.f / (1.f + __expf(-(s2 + dbb[i])));
    float vs   = s3 + cv[i];
    cc[i] = beta * (vs - kdh) / nrmE;
  }
  {
    float c = cc[0]; float4 kv = kvs[0];
    ushort4 ou;
    ou.x = f2bf((xv.x + c*kv.x)*QSCALE); ou.y = f2bf((xv.y + c*kv.y)*QSCALE);
    ou.z = f2bf((xv.z + c*kv.z)*QSCALE); ou.w = f2bf((xv.w + c*kv.w)*QSCALE);
    *(ushort4*)(qk + (size_t)m*DD + t*4) = ou;
  }
  {
    float c = cc[1]; float4 kv = kvs[1];
    ushort4 ou;
    ou.x = f2bf(xv.x + c*kv.x); ou.y = f2bf(xv.y + c*kv.y);
    ou.z = f2bf(xv.z + c*kv.z); ou.w = f2bf(xv.w + c*kv.w);
    *(ushort4*)(qk + (size_t)MM*DD + (size_t)m*DD + t*4) = ou;
  }
  {
    float c = cc[2]; float4 kv = kvs[2];
    float4 vv = make_float4(xv.x + c*kv.x, xv.y + c*kv.y, xv.z + c*kv.z, xv.w + c*kv.w);
    float4 w3 = *(const float4*)(wv + 3*DD + t*4);
    float s = dot4f(vv, w3);
    #pragma unroll
    for (int off=1; off<16; off<<=1) s += __shfl_xor(s, off);
    if ((lane & 15) == 0) {
      int head = t >> 4;
      int b = m >> 11, srow = m & (SS-1);
      Vw[((size_t)(b*HH + head))*SS + srow] = s;
    }
  }
}

// ---------------------------------------------------------------------------
// Kernel 4: split-K QK^T flash. grid (SS/QB=16, 16, BB*KC), block 256.
// v9: QB=128 (R11 best) + 64-key tiles -> 7 in-loop barriers instead of 15.
// R12 showed barrier-free direct-global loses (scattered 64B reads, latency);
// cooperative LDS staging needs a barrier per tile, so cut barrier COUNT by
// doubling the tile. Staging = R3's HW-verified 2-loads/thread pattern;
// triple buffer 3x8KB + Vws 2KB = 26KB; counted vmcnt(2) (drain only in the
// tail). K-frag reads processed 2 row-groups at a time to cap VGPR (~85
// under the (256,5)=102 cap).
__global__ __launch_bounds__(256, 5) void flash_mfma(const u16* __restrict__ qb,
     const u16* __restrict__ kb, const float* __restrict__ Vw,
     float* __restrict__ l_arr, float* __restrict__ pv_arr) {
  const int qt = blockIdx.x, h = blockIdx.y;
  const int b = blockIdx.z >> 2, kc = blockIdx.z & 3;
  const int t = threadIdx.x, w = t>>6, lane = t&63, q15 = lane&15, quad = lane>>4;
  const int lr = lane>>3, lc = lane&7, gsw = lc ^ lr;
  const int sw = q15 & 7;
  __shared__ u16 Ks[3][64*64];          // 24 KB triple buffer (64-key tiles)
  __shared__ float Vws[KT_PER*64];      // 2 KB, whole chunk's V weights
  const size_t hb = (size_t)h*HD;
  const u16* kbase = kb + (size_t)(b*SS + kc*KT_PER*64)*DD + hb;
  const float* vwb = Vw + (size_t)(b*HH + h)*SS + kc*KT_PER*64;

  // Q fragments for TWO q-sets straight from global (per-lane, once;
  // R11-proven: FETCH stays ~38MB, L2 absorbs)
  bf16x8 qf[2][2];
  #pragma unroll
  for (int qs=0; qs<2; qs++) {
    const u16* qrow = qb + (size_t)(b*SS + qt*QB + qs*64 + w*16 + q15)*DD + hb;
    qf[qs][0] = *(const bf16x8*)(qrow + quad*8);
    qf[qs][1] = *(const bf16x8*)(qrow + 32 + quad*8);
  }
  // Vw -> LDS (512 floats)
  if (t < KT_PER*64/4) {
    float4 v = *(const float4*)(vwb + t*4);
    *(float4*)(&Vws[t*4]) = v;
  }
  // stage K tiles 0 and 1 (R3-verified pattern: 2 gl_lds16/thread per tile)
  #pragma unroll
  for (int j=0; j<2; j++) {
    int r = (w*2+j)*8 + lr;
    gl_lds16(kbase + (size_t)r*DD + gsw*8,        &Ks[0][((w*2+j)*8)*64]);
    gl_lds16(kbase + (size_t)(64 + r)*DD + gsw*8, &Ks[1][((w*2+j)*8)*64]);
  }
  float l_acc[2] = {0.f,0.f}, pv_acc[2] = {0.f,0.f};
  __syncthreads();   // prologue-only full drain: qf via dep, K0,K1,Vws visible

  #pragma unroll
  for (int kt=0; kt<KT_PER; kt++) {
    // DMA tile kt+2 into buf[(kt+2)%3] (region last read at kt-1, barrier'd)
    if (kt+2 < KT_PER) {
      #pragma unroll
      for (int j=0; j<2; j++) {
        int r = (w*2+j)*8 + lr;
        gl_lds16(kbase + (size_t)((kt+2)*64 + r)*DD + gsw*8,
                 &Ks[(kt+2)%3][((w*2+j)*8)*64]);
      }
    }
    const u16* Kt = &Ks[kt%3][0];
    // 4 row-groups of 16 keys, processed 2 at a time (VGPR cap);
    // kf reads SHARED by both q-sets.
    #pragma unroll
    for (int gp=0; gp<2; gp++) {
      bf16x8 kf[2][2];
      #pragma unroll
      for (int g2=0; g2<2; g2++)
        #pragma unroll
        for (int kk=0; kk<2; kk++)
          kf[g2][kk] = *(const bf16x8*)(Kt + ((gp*2+g2)*16 + q15)*64
                                           + (((kk*4+quad)^sw)<<3));
      float4 va0 = *(const float4*)(&Vws[kt*64 + (gp*2+0)*16 + quad*4]);
      float4 va1 = *(const float4*)(&Vws[kt*64 + (gp*2+1)*16 + quad*4]);
      #pragma unroll
      for (int qs=0; qs<2; qs++) {
        f32x4 S0 = (f32x4){0.f,0.f,0.f,0.f}, S1 = (f32x4){0.f,0.f,0.f,0.f};
        #pragma unroll
        for (int kk=0; kk<2; kk++) {
          S0 = __builtin_amdgcn_mfma_f32_16x16x32_bf16(kf[0][kk], qf[qs][kk], S0, 0,0,0);
          S1 = __builtin_amdgcn_mfma_f32_16x16x32_bf16(kf[1][kk], qf[qs][kk], S1, 0,0,0);
        }
        {
          float p0 = EXP2F(fminf(S0[0], 30.f));
          float p1 = EXP2F(fminf(S0[1], 30.f));
          float p2 = EXP2F(fminf(S0[2], 30.f));
          float p3 = EXP2F(fminf(S0[3], 30.f));
          l_acc[qs]  += (p0 + p1) + (p2 + p3);
          pv_acc[qs] += p0*va0.x + p1*va0.y + p2*va0.z + p3*va0.w;
        }
        {
          float p0 = EXP2F(fminf(S1[0], 30.f));
          float p1 = EXP2F(fminf(S1[1], 30.f));
          float p2 = EXP2F(fminf(S1[2], 30.f));
          float p3 = EXP2F(fminf(S1[3], 30.f));
          l_acc[qs]  += (p0 + p1) + (p2 + p3);
          pv_acc[qs] += p0*va1.x + p1*va1.y + p2*va1.z + p3*va1.w;
        }
      }
    }
    // counted wait: only tile kt+2's 2 loads may stay outstanding ->
    // tile kt+1 is guaranteed landed; raw barrier releases buf[kt%3].
    if (kt < KT_PER-1) {
      __builtin_amdgcn_sched_barrier(0);
      if (kt+2 < KT_PER) asm volatile("s_waitcnt vmcnt(2)" ::: "memory");
      else               asm volatile("s_waitcnt vmcnt(0)" ::: "memory");
      __builtin_amdgcn_s_barrier();
      __builtin_amdgcn_sched_barrier(0);
    }
  }
  // reduce across quads (lanes sharing q column q15)
  #pragma unroll
  for (int qs=0; qs<2; qs++) {
    l_acc[qs]  += __shfl_xor(l_acc[qs], 16);  l_acc[qs]  += __shfl_xor(l_acc[qs], 32);
    pv_acc[qs] += __shfl_xor(pv_acc[qs], 16); pv_acc[qs] += __shfl_xor(pv_acc[qs], 32);
  }
  if (quad == 0) {
    #pragma unroll
    for (int qs=0; qs<2; qs++) {
      int tok = b*SS + qt*QB + qs*64 + w*16 + q15;
      size_t idx = ((size_t)kc*MM + tok)*HH + h;
      l_arr[idx]  = l_acc[qs];
      pv_arr[idx] = pv_acc[qs];
    }
  }
}

// ---------------------------------------------------------------------------
// Kernel 5: v3 = sum_h (sum_kc pv)/(sum_kc l), delta #3 + LayerNorm. grid MM.
__global__ void final_kernel(const float* __restrict__ x, const u16* __restrict__ kraw3,
                             const float* __restrict__ l_arr, const float* __restrict__ pv_arr,
                             const float* __restrict__ dbw, const float* __restrict__ dbb,
                             const float* __restrict__ cv,
                             const float* __restrict__ ln_g, const float* __restrict__ ln_b,
                             float* __restrict__ out) {
  int m = blockIdx.x, t = threadIdx.x, w = t>>6, lane = t&63;
  const float* xr = x     + (size_t)m*DD;
  const u16*   kr = kraw3 + (size_t)m*DD;
  float4 xv  = *(const float4*)(xr + t*4);
  ushort4 ku = *(const ushort4*)(kr + t*4);
  float4 kv  = make_float4(bf2f(ku.x), bf2f(ku.y), bf2f(ku.z), bf2f(ku.w));
  float4 bwv = *(const float4*)(dbw + 3*DD + t*4);
  __shared__ float4 part[4];
  __shared__ float2 part2[4];
  __shared__ float v3s;
  if (t < 16) {
    float lsum = 0.f, psum = 0.f;
    #pragma unroll
    for (int kc=0; kc<KC; kc++) {
      size_t idx = ((size_t)kc*MM + m)*HH + t;
      lsum += l_arr[idx];
      psum += pv_arr[idx];
    }
    float val = psum / lsum;
    #pragma unroll
    for (int off=1; off<16; off<<=1) val += __shfl_xor(val, off);
    if (t==0) v3s = val;
  }
  float4 red = make_float4(dot4f(kv,kv), dot4f(kv,xv), dot4f(xv,bwv), 0.f);
  red = wsum64_f4(red);
  if (lane==63) part[w] = red;
  __syncthreads();
  float4 r0=part[0], r1=part[1], r2=part[2], r3=part[3];
  float s0=r0.x+r1.x+r2.x+r3.x, s1=r0.y+r1.y+r2.y+r3.y, s2=r0.z+r1.z+r2.z+r3.z;
  float nrmE = sqrtf(s0) + 1e-8f;
  float kdh  = s1 / nrmE;
  float beta = 2.f / (1.f + __expf(-(s2 + dbb[3])));
  float v3   = v3s + cv[3];
  float c = beta * (v3 - kdh) / nrmE;
  float y0 = xv.x + c*kv.x, y1 = xv.y + c*kv.y, y2 = xv.z + c*kv.z, y3 = xv.w + c*kv.w;
  float2 rr = make_float2(y0+y1+y2+y3, y0*y0+y1*y1+y2*y2+y3*y3);
  rr = wsum64_f2(rr);
  if (lane==63) part2[w] = rr;
  __syncthreads();
  float ssum = part2[0].x+part2[1].x+part2[2].x+part2[3].x;
  float ssq  = part2[0].y+part2[1].y+part2[2].y+part2[3].y;
  float mu   = ssum * (1.f/DD);
  float var  = ssq * (1.f/DD) - mu*mu;
  float rstd = rsqrtf(var + 1e-5f);
  float4 g  = *(const float4*)(ln_g + t*4);
  float4 bb = *(const float4*)(ln_b + t*4);
  float4 ov;
  ov.x = (y0-mu)*rstd*g.x + bb.x;
  ov.y = (y1-mu)*rstd*g.y + bb.y;
  ov.z = (y2-mu)*rstd*g.z + bb.z;
  ov.w = (y3-mu)*rstd*g.w + bb.w;
  *(float4*)(out + (size_t)m*DD + t*4) = ov;
}

// ---------------------------------------------------------------------------
extern "C" void kernel_launch(void* const* d_in, const int* in_sizes, int n_in,
                              void* d_out, int out_size, void* d_ws, size_t ws_size,
                              hipStream_t stream) {
  const float* x    = (const float*)d_in[0];
  const float* Wq_  = (const float*)d_in[1];
  const float* bq_  = (const float*)d_in[2];
  const float* Wk_  = (const float*)d_in[3];
  const float* bk_  = (const float*)d_in[4];
  const float* Wv_  = (const float*)d_in[5];
  const float* bv_  = (const float*)d_in[6];
  const float* Wo_  = (const float*)d_in[7];
  const float* bo_  = (const float*)d_in[8];
  const float* dWk  = (const float*)d_in[9];
  const float* dbw  = (const float*)d_in[10];
  const float* dbb  = (const float*)d_in[11];
  const float* dWv  = (const float*)d_in[12];
  const float* dbv  = (const float*)d_in[13];
  const float* ln_g = (const float*)d_in[14];
  const float* ln_b = (const float*)d_in[15];
  float* out = (float*)d_out;
  char* WS = (char*)d_ws;

  // workspace layout (bytes):
  float* wv     = (float*)WS;                                 // 16 KB
  float* cv     = (float*)(WS + 16384);                       // 256 B
  u16*   kraw   = (u16*)  (WS + 16640);                       // 4*MM*DD bf16 = 33.5 MB
  u16*   qk     = (u16*)  (WS + 16640 + (size_t)4*MM*DD*2);   // 2*MM*DD bf16 = 16.8 MB
  u16*   dWkT   = (u16*)  (WS + 16640 + (size_t)6*MM*DD*2);   // 8.4 MB
  u16*   xb     = (u16*)  (WS + 16640 + (size_t)6*MM*DD*2 + (size_t)4*DD*DD*2); // 8.4 MB
  char*  tail   = WS + 16640 + (size_t)6*MM*DD*2 + (size_t)8*DD*DD*2;
  float* Vw     = (float*)tail;                               // BB*HH*SS f32 = 256 KB
  float* l_arr  = (float*)(tail + (size_t)BB*HH*SS*4);        // KC*MM*HH f32 = 1 MB
  float* pv_arr = (float*)(tail + (size_t)BB*HH*SS*4 + (size_t)KC*MM*HH*4); // 1 MB

  prep_kernel<<<NB_PREP, 256, 0, stream>>>(
      x, xb, dWk, dWkT, Wq_,bq_,Wk_,bk_,Wv_,bv_,Wo_,bo_, dWv, dbv, wv, cv);
  gemm_dwk_8ph<<<256, 512, 0, stream>>>(xb, dWkT, kraw);
  delta_qkv_kernel<<<MM, 256, 0, stream>>>(x, kraw, dbw, dbb, wv, cv, qk, Vw);
  flash_mfma<<<dim3(SS/QB, HH, BB*KC), 256, 0, stream>>>(
      qk, qk + (size_t)MM*DD, Vw, l_arr, pv_arr);
  final_kernel<<<MM, 256, 0, stream>>>(x, kraw + 3*(size_t)MM*DD, l_arr, pv_arr,
                                       dbw, dbb, cv, ln_g, ln_b, out);
}